// Round 17
// baseline (724.278 us; speedup 1.0000x reference)
//
#include <hip/hip_runtime.h>
#include <cstdint>

#define NN 50000
#define NE 800000
#define IN_DIM 16
#define H 32
#define EDGE_DIM 4
#define T_STEPS 4
#define NPB 64                        // nodes per block (4 waves x 16)
#define NBLK ((NN + NPB - 1) / NPB)   // 782
#define SBLK 196                      // scan blocks (196*256 >= NN+1)

typedef __bf16 bf16x8 __attribute__((ext_vector_type(8)));
typedef float f32x4 __attribute__((ext_vector_type(4)));
typedef unsigned int u32x4 __attribute__((ext_vector_type(4)));

__device__ __forceinline__ uint32_t bf_rne1(float f) {
    uint32_t u = __float_as_uint(f);
    return (u + 0x7FFFu + ((u >> 16) & 1u)) >> 16;
}
__device__ __forceinline__ float bf2f(uint32_t h16) { return __uint_as_float(h16 << 16); }
__device__ __forceinline__ uint32_t bfpair(float a, float b) {
    return (bf_rne1(b) << 16) | bf_rne1(a);
}
__device__ __forceinline__ bf16x8 asbf(u32x4 u) { return __builtin_bit_cast(bf16x8, u); }
__device__ __forceinline__ f32x4 MFMA(bf16x8 a, bf16x8 b, f32x4 c) {
    return __builtin_amdgcn_mfma_f32_16x16x32_bf16(a, b, c, 0, 0, 0);
}
// packed 2xbf16 (RNE) via the HW pack op; dst.lo=cvt(a), dst.hi=cvt(b)
__device__ __forceinline__ uint32_t cvt_pk_bf16(float a, float b) {
    uint32_t r;
    asm("v_cvt_pk_bf16_f32 %0, %1, %2" : "=v"(r) : "v"(a), "v"(b));
    return r;
}
// hi/lo split of a pair (residual in lo), returned by value (vector elems can't bind to refs)
__device__ __forceinline__ uint2 split_pair(float m0, float m1) {
    uint32_t hi = cvt_pk_bf16(m0, m1);
    float h0 = __uint_as_float(hi << 16);
    float h1 = __uint_as_float(hi & 0xFFFF0000u);
    uint32_t lo = cvt_pk_bf16(m0 - h0, m1 - h1);
    return make_uint2(hi, lo);
}

// packed h row: 32 u32 = 128B. words [0..15] = hi in fragment order
// (pk[4kg..4kg+3] = orig hi words {2kg,2kg+1,8+2kg,8+2kg+1}), [16..31] = lo same order.
__device__ __forceinline__ void store_hpk(uint32_t* hpk, int n, int cq, float4 a) {
    int off = (cq & 3) * 4 + (cq >> 2) * 2;
    uint32_t p0 = bfpair(a.x, a.y), p1 = bfpair(a.z, a.w);
    *(uint2*)(hpk + (size_t)n * 32 + off) = make_uint2(p0, p1);
    float r0 = a.x - bf2f(p0 & 0xFFFFu), r1 = a.y - bf2f(p0 >> 16);
    float r2 = a.z - bf2f(p1 & 0xFFFFu), r3 = a.w - bf2f(p1 >> 16);
    *(uint2*)(hpk + (size_t)n * 32 + 16 + off) = make_uint2(bfpair(r0, r1), bfpair(r2, r3));
}

// ---------------- embedding ----------------
__global__ __launch_bounds__(256) void embed_kernel(const float* __restrict__ inputs,
                                                    const float* __restrict__ W_emb,
                                                    float* __restrict__ h,
                                                    uint32_t* __restrict__ hpk) {
    int idx = blockIdx.x * 256 + threadIdx.x;
    if (idx >= NN * 8) return;
    int n = idx >> 3, cq = idx & 7;
    const float* xr = inputs + (size_t)n * IN_DIM;
    float4 a = make_float4(0.f, 0.f, 0.f, 0.f);
#pragma unroll
    for (int k = 0; k < IN_DIM; ++k) {
        float xk = xr[k];
        float4 w = *(const float4*)(W_emb + k * 32 + cq * 4);
        a.x = fmaf(xk, w.x, a.x); a.y = fmaf(xk, w.y, a.y);
        a.z = fmaf(xk, w.z, a.z); a.w = fmaf(xk, w.w, a.w);
    }
    *(float4*)(h + (size_t)n * 32 + cq * 4) = a;
    store_hpk(hpk, n, cq, a);
}

// ---------------- CSR build ----------------
__global__ __launch_bounds__(256) void hist_kernel(const int* __restrict__ dst, int* __restrict__ deg) {
    int e = blockIdx.x * 256 + threadIdx.x;
    if (e < NE) atomicAdd(&deg[dst[e]], 1);
}

__global__ __launch_bounds__(256) void scan_part(const int* __restrict__ deg, int* __restrict__ bsum) {
    __shared__ int red[256];
    int i = blockIdx.x * 256 + threadIdx.x;
    red[threadIdx.x] = (i < NN) ? deg[i] : 0;
    __syncthreads();
    for (int off = 128; off > 0; off >>= 1) {
        if (threadIdx.x < off) red[threadIdx.x] += red[threadIdx.x + off];
        __syncthreads();
    }
    if (threadIdx.x == 0) bsum[blockIdx.x] = red[0];
}

__global__ __launch_bounds__(256) void scan_tops(const int* __restrict__ bsum, int* __restrict__ btop) {
    __shared__ int s[256];
    int tid = threadIdx.x;
    int v0 = (tid < SBLK) ? bsum[tid] : 0;
    s[tid] = v0;
    __syncthreads();
    for (int off = 1; off < 256; off <<= 1) {
        int v = (tid >= off) ? s[tid - off] : 0;
        __syncthreads();
        s[tid] += v;
        __syncthreads();
    }
    if (tid < SBLK) btop[tid] = s[tid] - v0;   // exclusive
}

__global__ __launch_bounds__(256) void scan_final(const int* __restrict__ deg,
                                                  const int* __restrict__ btop,
                                                  int* __restrict__ row_ptr) {
    __shared__ int s[256];
    int tid = threadIdx.x;
    int i = blockIdx.x * 256 + tid;
    int v0 = (i < NN) ? deg[i] : 0;
    s[tid] = v0;
    __syncthreads();
    for (int off = 1; off < 256; off <<= 1) {
        int v = (tid >= off) ? s[tid - off] : 0;
        __syncthreads();
        s[tid] += v;
        __syncthreads();
    }
    if (i <= NN) row_ptr[i] = btop[blockIdx.x] + s[tid] - v0;
}

__global__ __launch_bounds__(256) void scatter_kernel(const int* __restrict__ src, const int* __restrict__ dst,
                                                      const int* __restrict__ row_ptr, int* __restrict__ cnt,
                                                      uint2* __restrict__ se_sorted) {
    int e = blockIdx.x * 256 + threadIdx.x;
    if (e >= NE) return;
    int d = dst[e];
    int pos = row_ptr[d] + atomicAdd(&cnt[d], 1);
    se_sorted[pos] = make_uint2((unsigned)src[e], (unsigned)e);
}

// ---------------- ef re-layout: packed {hi0,hi1,lo0,lo1} per (t,p) ----------------
__global__ __launch_bounds__(256) void ef_sort_kernel(const float* __restrict__ e_feats,
                                                      const uint2* __restrict__ se_sorted,
                                                      u32x4* __restrict__ ef4) {
    int p = blockIdx.x * 256 + threadIdx.x;
    if (p >= NE) return;
    int e = (int)se_sorted[p].y;
    float buf[16];
    const float4* srcp = (const float4*)(e_feats + (size_t)e * (EDGE_DIM * T_STEPS));
#pragma unroll
    for (int q = 0; q < 4; ++q) {
        float4 v = srcp[q];
        buf[4 * q + 0] = v.x; buf[4 * q + 1] = v.y; buf[4 * q + 2] = v.z; buf[4 * q + 3] = v.w;
    }
#pragma unroll
    for (int t = 0; t < T_STEPS; ++t) {
        float f0 = buf[t], f1 = buf[4 + t], f2 = buf[8 + t], f3 = buf[12 + t];
        uint32_t h0 = bfpair(f0, f1), h1 = bfpair(f2, f3);
        float r0 = f0 - bf2f(h0 & 0xFFFFu), r1 = f1 - bf2f(h0 >> 16);
        float r2 = f2 - bf2f(h1 & 0xFFFFu), r3 = f3 - bf2f(h1 >> 16);
        u32x4 o = {h0, h1, bfpair(r0, r1), bfpair(r2, r3)};
        ef4[(size_t)t * NE + p] = o;
    }
}

// ---------------- We -> B-fragment prep (r7-verified layout) ----------------
__global__ __launch_bounds__(256) void wefrag_kernel(const float* __restrict__ We_in,
                                                     const float* __restrict__ We_out,
                                                     u32x4* __restrict__ frag) {
    int idx = blockIdx.x * 256 + threadIdx.x;
    if (idx >= 3 * 2 * 2 * 2 * 64) return;
    int lane = idx & 63;
    int hl = (idx >> 6) & 1;
    int nt = (idx >> 7) & 1;
    int ks = (idx >> 8) & 1;
    int mat = idx >> 9;
    const float* W = (mat < 2) ? (We_in + (size_t)mat * 36 * 32) : We_out;
    int col = (lane & 15) + nt * 16;
    int kb = ks * 32 + ((lane >> 4) & 3) * 4;
    u32x4 o;
#pragma unroll
    for (int i = 0; i < 4; ++i) {
        int k0 = kb + (i >= 2 ? 16 : 0) + (i & 1) * 2;
        float v0 = (k0 < 36) ? W[(size_t)k0 * 32 + col] : 0.f;
        float v1 = (k0 + 1 < 36) ? W[(size_t)(k0 + 1) * 32 + col] : 0.f;
        if (hl) {
            v0 -= bf2f(bf_rne1(v0));
            v1 -= bf2f(bf_rne1(v1));
        }
        o[i] = bfpair(v0, v1);
    }
    frag[idx] = o;
}

// ---------------- fused layer: barrier-free, MFMA msg + MFMA aggregation ----------------
// Wave owns 16 dst nodes. Per 32-edge pair: msg = relu(X @ We) via 24 MFMAs; messages stay
// in registers (cvt_pk bf16 hi/lo), aggregated by 4 sel-MFMAs (sel = exact 0/1 CSR mask).
// No msg LDS, no serial segsum, no __syncthreads anywhere.
__global__ __launch_bounds__(256) void layer_kernel(const float* __restrict__ h,
                                                    const uint32_t* __restrict__ hpk,
                                                    const u32x4* __restrict__ ef4,
                                                    const uint2* __restrict__ se,
                                                    const int* __restrict__ row_ptr,
                                                    const float* __restrict__ rain0,
                                                    const u32x4* __restrict__ wfrag,
                                                    const float* __restrict__ Wn,
                                                    const float* __restrict__ Wrain,
                                                    float* __restrict__ hnew,
                                                    uint32_t* __restrict__ hnpk,
                                                    float* __restrict__ out,
                                                    int t, int last) {
    __shared__ float shl[NPB * 36];        // own nodes' h
    __shared__ float sagg[NPB * 36];       // aggregated messages

    int tid = threadIdx.x;
    int lane = tid & 63, w = tid >> 6;
    int nb0 = blockIdx.x * NPB;
    int nbw = nb0 + w * 16;                // this wave's first node
    int l15 = lane & 15, kg = lane >> 4;

    // wave-local CSR pointers (lanes 0..16 meaningful)
    int rpv = row_ptr[min(nbw + min(lane, 16), NN)];
    int e0w = __shfl(rpv, 0);
    int e1w = __shfl(rpv, 16);
    int arb = __shfl(rpv, l15);            // node l15 range (for sel rows)
    int are = __shfl(rpv, l15 + 1);

    // stage own 16 nodes' h rows (wave-local)
#pragma unroll
    for (int it = 0; it < 2; ++it) {
        int idx = it * 64 + lane;          // 128 float4 = 16 nodes x 8 quads
        int nl = w * 16 + (idx >> 3), q = idx & 7;
        int n = nb0 + nl;
        if (n < NN)
            *(float4*)&shl[nl * 36 + q * 4] = *(const float4*)(h + (size_t)n * 32 + q * 4);
    }

    // hoist We B-fragments into registers
    u32x4 b[2][2][2];
#pragma unroll
    for (int ks = 0; ks < 2; ++ks)
#pragma unroll
        for (int nt = 0; nt < 2; ++nt)
#pragma unroll
            for (int hl = 0; hl < 2; ++hl)
                b[ks][nt][hl] = wfrag[((ks * 2 + nt) * 2 + hl) * 64 + lane];

    struct Frag { u32x4 ah, al, e4; };
    auto loadFrag = [&](int i) -> Frag {   // i = 16-edge tile index
        Frag f;
        int p = e0w + i * 16 + l15;
        int pc = p < e1w ? p : e1w - 1;
        int s = (int)se[pc].x;
        const u32x4* hp = (const u32x4*)(hpk + (size_t)s * 32);
        f.ah = hp[kg];
        f.al = hp[4 + kg];
        f.e4 = (kg == 0) ? ef4[pc] : u32x4{0u, 0u, 0u, 0u};
        return f;
    };
    auto computeMsg = [&](Frag f, f32x4& c0, f32x4& c1) {
        u32x4 a1h = {f.e4[0], f.e4[1], 0u, 0u};
        u32x4 a1l = {f.e4[2], f.e4[3], 0u, 0u};
        bf16x8 Ah = asbf(f.ah), Al = asbf(f.al), Eh = asbf(a1h), El = asbf(a1l);
        c0 = MFMA(Ah, asbf(b[0][0][0]), c0);
        c0 = MFMA(Ah, asbf(b[0][0][1]), c0);
        c0 = MFMA(Al, asbf(b[0][0][0]), c0);
        c0 = MFMA(Eh, asbf(b[1][0][0]), c0);
        c0 = MFMA(Eh, asbf(b[1][0][1]), c0);
        c0 = MFMA(El, asbf(b[1][0][0]), c0);
        c1 = MFMA(Ah, asbf(b[0][1][0]), c1);
        c1 = MFMA(Ah, asbf(b[0][1][1]), c1);
        c1 = MFMA(Al, asbf(b[0][1][0]), c1);
        c1 = MFMA(Eh, asbf(b[1][1][0]), c1);
        c1 = MFMA(Eh, asbf(b[1][1][1]), c1);
        c1 = MFMA(El, asbf(b[1][1][0]), c1);
    };

    f32x4 aggD0 = {0.f, 0.f, 0.f, 0.f};   // agg[node (kg*4+r)][ch l15]
    f32x4 aggD1 = {0.f, 0.f, 0.f, 0.f};   // same, ch l15+16
    int kb4 = kg * 4;

    if (e1w > e0w) {
        int nP = (e1w - e0w + 31) >> 5;    // 32-edge pairs
        Frag fa0 = loadFrag(0), fb0 = loadFrag(1);
        Frag fa1 = loadFrag(2), fb1 = loadFrag(3);
#pragma unroll 1
        for (int i = 0; i < nP; ++i) {
            Frag fan = loadFrag((i + 2) * 2);
            Frag fbn = loadFrag((i + 2) * 2 + 1);
            // messages for 32 edges (2 tiles), held in registers
            f32x4 c0A = {0.f,0.f,0.f,0.f}, c1A = {0.f,0.f,0.f,0.f};
            f32x4 c0B = {0.f,0.f,0.f,0.f}, c1B = {0.f,0.f,0.f,0.f};
            computeMsg(fa0, c0A, c1A);
            computeMsg(fb0, c0B, c1B);
            // relu
#pragma unroll
            for (int r = 0; r < 4; ++r) {
                c0A[r] = fmaxf(c0A[r], 0.f); c1A[r] = fmaxf(c1A[r], 0.f);
                c0B[r] = fmaxf(c0B[r], 0.f); c1B[r] = fmaxf(c1B[r], 0.f);
            }
            // msg -> B-fragment (bf16 hi/lo), pure register traffic
            u32x4 Bh0, Bl0, Bh1, Bl1;
            uint2 sp;
            sp = split_pair(c0A[0], c0A[1]); Bh0[0] = sp.x; Bl0[0] = sp.y;
            sp = split_pair(c0A[2], c0A[3]); Bh0[1] = sp.x; Bl0[1] = sp.y;
            sp = split_pair(c0B[0], c0B[1]); Bh0[2] = sp.x; Bl0[2] = sp.y;
            sp = split_pair(c0B[2], c0B[3]); Bh0[3] = sp.x; Bl0[3] = sp.y;
            sp = split_pair(c1A[0], c1A[1]); Bh1[0] = sp.x; Bl1[0] = sp.y;
            sp = split_pair(c1A[2], c1A[3]); Bh1[1] = sp.x; Bl1[1] = sp.y;
            sp = split_pair(c1B[0], c1B[1]); Bh1[2] = sp.x; Bl1[2] = sp.y;
            sp = split_pair(c1B[2], c1B[3]); Bh1[3] = sp.x; Bl1[3] = sp.y;
            // sel A-fragment: row = node l15, k = edge (exact 0/1 in bf16)
            int tb = e0w + i * 32;
            u32x4 S;
#pragma unroll
            for (int j = 0; j < 4; ++j) {
                int k0 = kb4 + (j & 1) * 2 + ((j >= 2) ? 16 : 0);
                int p0 = tb + k0, p1 = p0 + 1;
                uint32_t s0 = ((unsigned)(p0 - arb) < (unsigned)(are - arb)) ? 0x3F80u : 0u;
                uint32_t s1 = ((unsigned)(p1 - arb) < (unsigned)(are - arb)) ? 0x3F800000u : 0u;
                S[j] = s0 | s1;
            }
            bf16x8 selA = asbf(S);
            aggD0 = MFMA(selA, asbf(Bh0), aggD0);
            aggD0 = MFMA(selA, asbf(Bl0), aggD0);
            aggD1 = MFMA(selA, asbf(Bh1), aggD1);
            aggD1 = MFMA(selA, asbf(Bl1), aggD1);
            fa0 = fa1; fb0 = fb1; fa1 = fan; fb1 = fbn;
        }
    }
    // write agg to LDS: lane holds nodes kg*4+r, ch l15 / l15+16
#pragma unroll
    for (int r = 0; r < 4; ++r) {
        int nl = w * 16 + kg * 4 + r;
        sagg[nl * 36 + l15] = aggD0[r];
        sagg[nl * 36 + 16 + l15] = aggD1[r];
    }

    // ---- node phase (wave-local, 2 passes of 8 nodes): lane -> node sg, channels sl*4..+3 ----
    int sg = lane >> 3, sl = lane & 7;
#pragma unroll
    for (int pass = 0; pass < 2; ++pass) {
        int nl = w * 16 + pass * 8 + sg;
        int n = nb0 + nl;
        if (n < NN) {
            float4 a = make_float4(0.f, 0.f, 0.f, 0.f);
#pragma unroll 8
            for (int k = 0; k < 32; ++k) {
                float xk = shl[nl * 36 + k];
                float4 wv = *(const float4*)(Wn + (size_t)k * 32 + sl * 4);
                a.x = fmaf(xk, wv.x, a.x); a.y = fmaf(xk, wv.y, a.y);
                a.z = fmaf(xk, wv.z, a.z); a.w = fmaf(xk, wv.w, a.w);
            }
#pragma unroll 8
            for (int k = 0; k < 32; ++k) {
                float xk = sagg[nl * 36 + k];
                float4 wv = *(const float4*)(Wn + (size_t)(32 + k) * 32 + sl * 4);
                a.x = fmaf(xk, wv.x, a.x); a.y = fmaf(xk, wv.y, a.y);
                a.z = fmaf(xk, wv.z, a.z); a.w = fmaf(xk, wv.w, a.w);
            }
            {
                float rain = rain0[(size_t)n * T_STEPS + t];
                float4 wv = *(const float4*)(Wn + (size_t)64 * 32 + sl * 4);
                a.x = fmaf(rain, wv.x, a.x); a.y = fmaf(rain, wv.y, a.y);
                a.z = fmaf(rain, wv.z, a.z); a.w = fmaf(rain, wv.w, a.w);
            }
            a.x = fmaxf(a.x, 0.f); a.y = fmaxf(a.y, 0.f);
            a.z = fmaxf(a.z, 0.f); a.w = fmaxf(a.w, 0.f);
            *(float4*)(hnew + (size_t)n * 32 + sl * 4) = a;
            store_hpk(hnpk, n, sl, a);
            if (last) {
                float4 wr = *(const float4*)(Wrain + sl * 4);
                float rv = a.x * wr.x + a.y * wr.y + a.z * wr.z + a.w * wr.w;
                rv += __shfl_xor(rv, 1);
                rv += __shfl_xor(rv, 2);
                rv += __shfl_xor(rv, 4);
                if (sl == 0) out[(size_t)n * T_STEPS + t] = rv;
            }
        }
    }
}

extern "C" void kernel_launch(void* const* d_in, const int* in_sizes, int n_in,
                              void* d_out, int out_size, void* d_ws, size_t ws_size,
                              hipStream_t stream) {
    const float* inputs     = (const float*)d_in[0];
    const float* e_feats    = (const float*)d_in[1];
    const float* rain0      = (const float*)d_in[2];
    const float* W_emb      = (const float*)d_in[3];
    const float* W_edge_in  = (const float*)d_in[4];
    const float* W_node_in  = (const float*)d_in[5];
    const float* W_edge_out = (const float*)d_in[6];
    const float* W_node_out = (const float*)d_in[7];
    const float* W_rain     = (const float*)d_in[8];
    const int*   src        = (const int*)d_in[9];
    const int*   dst        = (const int*)d_in[10];
    float* out = (float*)d_out;

    // workspace layout (~84 MB)
    float* h_a = (float*)d_ws;                                   // NN*32
    float* h_b = h_a + (size_t)NN * 32;                          // NN*32
    uint32_t* hpk_a = (uint32_t*)(h_b + (size_t)NN * 32);        // NN*32 u32
    uint32_t* hpk_b = hpk_a + (size_t)NN * 32;                   // NN*32 u32
    u32x4* ef4      = (u32x4*)(hpk_b + (size_t)NN * 32);         // T*NE u32x4
    u32x4* wfrag    = ef4 + (size_t)T_STEPS * NE;                // 1536
    int* row_ptr    = (int*)(wfrag + 1536);                      // NN+1
    int* deg        = row_ptr + (NN + 1);                        // NN
    int* cnt        = deg + NN;                                  // NN
    uint2* se       = (uint2*)(cnt + NN + 1);                    // NE (8B aligned)
    int* bsum       = (int*)(se + NE);                           // SBLK
    int* btop       = bsum + SBLK;                               // SBLK

    embed_kernel<<<(NN * 8 + 255) / 256, 256, 0, stream>>>(inputs, W_emb, h_a, hpk_a);

    // CSR build (hierarchical scan)
    hipMemsetAsync(deg, 0, (size_t)2 * NN * sizeof(int), stream);  // deg + cnt contiguous
    hist_kernel<<<(NE + 255) / 256, 256, 0, stream>>>(dst, deg);
    scan_part<<<SBLK, 256, 0, stream>>>(deg, bsum);
    scan_tops<<<1, 256, 0, stream>>>(bsum, btop);
    scan_final<<<SBLK, 256, 0, stream>>>(deg, btop, row_ptr);
    scatter_kernel<<<(NE + 255) / 256, 256, 0, stream>>>(src, dst, row_ptr, cnt, se);
    ef_sort_kernel<<<(NE + 255) / 256, 256, 0, stream>>>(e_feats, se, ef4);
    wefrag_kernel<<<6, 256, 0, stream>>>(W_edge_in, W_edge_out, wfrag);

    float* hc = h_a;  float* hn = h_b;
    uint32_t* pkc = hpk_a; uint32_t* pkn = hpk_b;
    for (int t = 0; t < T_STEPS; ++t) {
        const u32x4* ef4_t = ef4 + (size_t)t * NE;
        for (int s = 0; s < 3; ++s) {
            int mat = (s < 2) ? s : 2;
            const float* Wn = (s < 2) ? (W_node_in + (size_t)s * 65 * 32) : W_node_out;
            layer_kernel<<<NBLK, 256, 0, stream>>>(hc, pkc, ef4_t, se, row_ptr, rain0,
                                                   wfrag + (size_t)mat * 512, Wn, W_rain,
                                                   hn, pkn, out, t, (s == 2) ? 1 : 0);
            float* tf = hc; hc = hn; hn = tf;
            uint32_t* tp = pkc; pkc = pkn; pkn = tp;
        }
    }
}

// Round 18
// 651.052 us; speedup vs baseline: 1.1125x; 1.1125x over previous
//
#include <hip/hip_runtime.h>
#include <cstdint>

#define NN 50000
#define NE 800000
#define IN_DIM 16
#define H 32
#define EDGE_DIM 4
#define T_STEPS 4
#define NPB 32                        // nodes per block (4 waves x 8)
#define NBLK ((NN + NPB - 1) / NPB)   // 1563
#define SBLK 196                      // scan blocks (196*256 >= NN+1)

typedef __bf16 bf16x8 __attribute__((ext_vector_type(8)));
typedef float f32x4 __attribute__((ext_vector_type(4)));
typedef unsigned int u32x4 __attribute__((ext_vector_type(4)));

__device__ __forceinline__ uint32_t bf_rne1(float f) {
    uint32_t u = __float_as_uint(f);
    return (u + 0x7FFFu + ((u >> 16) & 1u)) >> 16;
}
__device__ __forceinline__ float bf2f(uint32_t h16) { return __uint_as_float(h16 << 16); }
__device__ __forceinline__ uint32_t bfpair(float a, float b) {
    return (bf_rne1(b) << 16) | bf_rne1(a);
}
__device__ __forceinline__ bf16x8 asbf(u32x4 u) { return __builtin_bit_cast(bf16x8, u); }
__device__ __forceinline__ f32x4 MFMA(bf16x8 a, bf16x8 b, f32x4 c) {
    return __builtin_amdgcn_mfma_f32_16x16x32_bf16(a, b, c, 0, 0, 0);
}
// packed 2xbf16 (RNE) via the HW pack op; dst.lo=cvt(a), dst.hi=cvt(b)
__device__ __forceinline__ uint32_t cvt_pk_bf16(float a, float b) {
    uint32_t r;
    asm("v_cvt_pk_bf16_f32 %0, %1, %2" : "=v"(r) : "v"(a), "v"(b));
    return r;
}
// hi/lo split of a pair (residual in lo), returned by value
__device__ __forceinline__ uint2 split_pair(float m0, float m1) {
    uint32_t hi = cvt_pk_bf16(m0, m1);
    float h0 = __uint_as_float(hi << 16);
    float h1 = __uint_as_float(hi & 0xFFFF0000u);
    uint32_t lo = cvt_pk_bf16(m0 - h0, m1 - h1);
    return make_uint2(hi, lo);
}

// packed h row: 32 u32 = 128B. words [0..15] = hi in fragment order
// (pk[4kg..4kg+3] = orig hi words {2kg,2kg+1,8+2kg,8+2kg+1}), [16..31] = lo same order.
__device__ __forceinline__ void store_hpk(uint32_t* hpk, int n, int cq, float4 a) {
    int off = (cq & 3) * 4 + (cq >> 2) * 2;
    uint32_t p0 = bfpair(a.x, a.y), p1 = bfpair(a.z, a.w);
    *(uint2*)(hpk + (size_t)n * 32 + off) = make_uint2(p0, p1);
    float r0 = a.x - bf2f(p0 & 0xFFFFu), r1 = a.y - bf2f(p0 >> 16);
    float r2 = a.z - bf2f(p1 & 0xFFFFu), r3 = a.w - bf2f(p1 >> 16);
    *(uint2*)(hpk + (size_t)n * 32 + 16 + off) = make_uint2(bfpair(r0, r1), bfpair(r2, r3));
}

// ---------------- embedding ----------------
__global__ __launch_bounds__(256) void embed_kernel(const float* __restrict__ inputs,
                                                    const float* __restrict__ W_emb,
                                                    float* __restrict__ h,
                                                    uint32_t* __restrict__ hpk) {
    int idx = blockIdx.x * 256 + threadIdx.x;
    if (idx >= NN * 8) return;
    int n = idx >> 3, cq = idx & 7;
    const float* xr = inputs + (size_t)n * IN_DIM;
    float4 a = make_float4(0.f, 0.f, 0.f, 0.f);
#pragma unroll
    for (int k = 0; k < IN_DIM; ++k) {
        float xk = xr[k];
        float4 w = *(const float4*)(W_emb + k * 32 + cq * 4);
        a.x = fmaf(xk, w.x, a.x); a.y = fmaf(xk, w.y, a.y);
        a.z = fmaf(xk, w.z, a.z); a.w = fmaf(xk, w.w, a.w);
    }
    *(float4*)(h + (size_t)n * 32 + cq * 4) = a;
    store_hpk(hpk, n, cq, a);
}

// ---------------- CSR build ----------------
__global__ __launch_bounds__(256) void hist_kernel(const int* __restrict__ dst, int* __restrict__ deg) {
    int e = blockIdx.x * 256 + threadIdx.x;
    if (e < NE) atomicAdd(&deg[dst[e]], 1);
}

__global__ __launch_bounds__(256) void scan_part(const int* __restrict__ deg, int* __restrict__ bsum) {
    __shared__ int red[256];
    int i = blockIdx.x * 256 + threadIdx.x;
    red[threadIdx.x] = (i < NN) ? deg[i] : 0;
    __syncthreads();
    for (int off = 128; off > 0; off >>= 1) {
        if (threadIdx.x < off) red[threadIdx.x] += red[threadIdx.x + off];
        __syncthreads();
    }
    if (threadIdx.x == 0) bsum[blockIdx.x] = red[0];
}

__global__ __launch_bounds__(256) void scan_tops(const int* __restrict__ bsum, int* __restrict__ btop) {
    __shared__ int s[256];
    int tid = threadIdx.x;
    int v0 = (tid < SBLK) ? bsum[tid] : 0;
    s[tid] = v0;
    __syncthreads();
    for (int off = 1; off < 256; off <<= 1) {
        int v = (tid >= off) ? s[tid - off] : 0;
        __syncthreads();
        s[tid] += v;
        __syncthreads();
    }
    if (tid < SBLK) btop[tid] = s[tid] - v0;   // exclusive
}

__global__ __launch_bounds__(256) void scan_final(const int* __restrict__ deg,
                                                  const int* __restrict__ btop,
                                                  int* __restrict__ row_ptr) {
    __shared__ int s[256];
    int tid = threadIdx.x;
    int i = blockIdx.x * 256 + tid;
    int v0 = (i < NN) ? deg[i] : 0;
    s[tid] = v0;
    __syncthreads();
    for (int off = 1; off < 256; off <<= 1) {
        int v = (tid >= off) ? s[tid - off] : 0;
        __syncthreads();
        s[tid] += v;
        __syncthreads();
    }
    if (i <= NN) row_ptr[i] = btop[blockIdx.x] + s[tid] - v0;
}

__global__ __launch_bounds__(256) void scatter_kernel(const int* __restrict__ src, const int* __restrict__ dst,
                                                      const int* __restrict__ row_ptr, int* __restrict__ cnt,
                                                      uint2* __restrict__ se_sorted) {
    int e = blockIdx.x * 256 + threadIdx.x;
    if (e >= NE) return;
    int d = dst[e];
    int pos = row_ptr[d] + atomicAdd(&cnt[d], 1);
    se_sorted[pos] = make_uint2((unsigned)src[e], (unsigned)e);
}

// ---------------- ef re-layout: packed {hi0,hi1,lo0,lo1} per (t,p) ----------------
__global__ __launch_bounds__(256) void ef_sort_kernel(const float* __restrict__ e_feats,
                                                      const uint2* __restrict__ se_sorted,
                                                      u32x4* __restrict__ ef4) {
    int p = blockIdx.x * 256 + threadIdx.x;
    if (p >= NE) return;
    int e = (int)se_sorted[p].y;
    float buf[16];
    const float4* srcp = (const float4*)(e_feats + (size_t)e * (EDGE_DIM * T_STEPS));
#pragma unroll
    for (int q = 0; q < 4; ++q) {
        float4 v = srcp[q];
        buf[4 * q + 0] = v.x; buf[4 * q + 1] = v.y; buf[4 * q + 2] = v.z; buf[4 * q + 3] = v.w;
    }
#pragma unroll
    for (int t = 0; t < T_STEPS; ++t) {
        float f0 = buf[t], f1 = buf[4 + t], f2 = buf[8 + t], f3 = buf[12 + t];
        uint32_t h0 = bfpair(f0, f1), h1 = bfpair(f2, f3);
        float r0 = f0 - bf2f(h0 & 0xFFFFu), r1 = f1 - bf2f(h0 >> 16);
        float r2 = f2 - bf2f(h1 & 0xFFFFu), r3 = f3 - bf2f(h1 >> 16);
        u32x4 o = {h0, h1, bfpair(r0, r1), bfpair(r2, r3)};
        ef4[(size_t)t * NE + p] = o;
    }
}

// ---------------- We -> B-fragment prep (r7-verified layout) ----------------
__global__ __launch_bounds__(256) void wefrag_kernel(const float* __restrict__ We_in,
                                                     const float* __restrict__ We_out,
                                                     u32x4* __restrict__ frag) {
    int idx = blockIdx.x * 256 + threadIdx.x;
    if (idx >= 3 * 2 * 2 * 2 * 64) return;
    int lane = idx & 63;
    int hl = (idx >> 6) & 1;
    int nt = (idx >> 7) & 1;
    int ks = (idx >> 8) & 1;
    int mat = idx >> 9;
    const float* W = (mat < 2) ? (We_in + (size_t)mat * 36 * 32) : We_out;
    int col = (lane & 15) + nt * 16;
    int kb = ks * 32 + ((lane >> 4) & 3) * 4;
    u32x4 o;
#pragma unroll
    for (int i = 0; i < 4; ++i) {
        int k0 = kb + (i >= 2 ? 16 : 0) + (i & 1) * 2;
        float v0 = (k0 < 36) ? W[(size_t)k0 * 32 + col] : 0.f;
        float v1 = (k0 + 1 < 36) ? W[(size_t)(k0 + 1) * 32 + col] : 0.f;
        if (hl) {
            v0 -= bf2f(bf_rne1(v0));
            v1 -= bf2f(bf_rne1(v1));
        }
        o[i] = bfpair(v0, v1);
    }
    frag[idx] = o;
}

// ---------------- fused layer: barrier-free, 8-node waves, MFMA msg + MFMA aggregation ----
// Wave owns 8 dst nodes (6250 waves total -> full TLP). Per 32-edge pair: msg = relu(X@We)
// via 24 MFMAs; messages stay in registers (cvt_pk bf16 hi/lo); aggregated by 4 sel-MFMAs
// (sel rows 0..7 = nodes, rows 8..15 masked zero). No msg LDS, no __syncthreads anywhere.
__global__ __launch_bounds__(256) void layer_kernel(const float* __restrict__ h,
                                                    const uint32_t* __restrict__ hpk,
                                                    const u32x4* __restrict__ ef4,
                                                    const uint2* __restrict__ se,
                                                    const int* __restrict__ row_ptr,
                                                    const float* __restrict__ rain0,
                                                    const u32x4* __restrict__ wfrag,
                                                    const float* __restrict__ Wn,
                                                    const float* __restrict__ Wrain,
                                                    float* __restrict__ hnew,
                                                    uint32_t* __restrict__ hnpk,
                                                    float* __restrict__ out,
                                                    int t, int last) {
    __shared__ float shl[NPB * 36];        // own nodes' h
    __shared__ float sagg[NPB * 36];       // aggregated messages

    int tid = threadIdx.x;
    int lane = tid & 63, w = tid >> 6;
    int nb0 = blockIdx.x * NPB;
    int nbw = nb0 + w * 8;                 // this wave's first node
    int l15 = lane & 15, kg = lane >> 4;

    // wave-local CSR pointers (lanes 0..8 meaningful)
    int rpv = row_ptr[min(nbw + min(lane, 8), NN)];
    int e0w = __shfl(rpv, 0);
    int e1w = __shfl(rpv, 8);
    // sel row l15 -> node l15 (empty range for l15 >= 8)
    int arb = __shfl(rpv, min(l15, 8));
    int are = __shfl(rpv, min(l15 + 1, 8));

    // stage own 8 nodes' h rows (wave-local; 1 float4 per lane)
    {
        int nl = w * 8 + (lane >> 3), q = lane & 7;
        int n = nb0 + nl;
        if (n < NN)
            *(float4*)&shl[nl * 36 + q * 4] = *(const float4*)(h + (size_t)n * 32 + q * 4);
    }

    // hoist We B-fragments into registers
    u32x4 b[2][2][2];
#pragma unroll
    for (int ks = 0; ks < 2; ++ks)
#pragma unroll
        for (int nt = 0; nt < 2; ++nt)
#pragma unroll
            for (int hl = 0; hl < 2; ++hl)
                b[ks][nt][hl] = wfrag[((ks * 2 + nt) * 2 + hl) * 64 + lane];

    struct Frag { u32x4 ah, al, e4; };
    auto loadFrag = [&](int i) -> Frag {   // i = 16-edge tile index
        Frag f;
        int p = e0w + i * 16 + l15;
        int pc = p < e1w ? p : e1w - 1;
        int s = (int)se[pc].x;
        const u32x4* hp = (const u32x4*)(hpk + (size_t)s * 32);
        f.ah = hp[kg];
        f.al = hp[4 + kg];
        f.e4 = (kg == 0) ? ef4[pc] : u32x4{0u, 0u, 0u, 0u};
        return f;
    };
    auto computeMsg = [&](Frag f, f32x4& c0, f32x4& c1) {
        u32x4 a1h = {f.e4[0], f.e4[1], 0u, 0u};
        u32x4 a1l = {f.e4[2], f.e4[3], 0u, 0u};
        bf16x8 Ah = asbf(f.ah), Al = asbf(f.al), Eh = asbf(a1h), El = asbf(a1l);
        c0 = MFMA(Ah, asbf(b[0][0][0]), c0);
        c0 = MFMA(Ah, asbf(b[0][0][1]), c0);
        c0 = MFMA(Al, asbf(b[0][0][0]), c0);
        c0 = MFMA(Eh, asbf(b[1][0][0]), c0);
        c0 = MFMA(Eh, asbf(b[1][0][1]), c0);
        c0 = MFMA(El, asbf(b[1][0][0]), c0);
        c1 = MFMA(Ah, asbf(b[0][1][0]), c1);
        c1 = MFMA(Ah, asbf(b[0][1][1]), c1);
        c1 = MFMA(Al, asbf(b[0][1][0]), c1);
        c1 = MFMA(Eh, asbf(b[1][1][0]), c1);
        c1 = MFMA(Eh, asbf(b[1][1][1]), c1);
        c1 = MFMA(El, asbf(b[1][1][0]), c1);
    };

    f32x4 aggD0 = {0.f, 0.f, 0.f, 0.f};   // agg[node (kg*4+r)][ch l15]    (kg<2 valid)
    f32x4 aggD1 = {0.f, 0.f, 0.f, 0.f};   // same, ch l15+16
    int kb4 = kg * 4;

    if (e1w > e0w) {
        int nP = (e1w - e0w + 31) >> 5;    // 32-edge pairs
        Frag fa0 = loadFrag(0), fb0 = loadFrag(1);
        Frag fa1 = loadFrag(2), fb1 = loadFrag(3);
#pragma unroll 1
        for (int i = 0; i < nP; ++i) {
            Frag fan = loadFrag((i + 2) * 2);
            Frag fbn = loadFrag((i + 2) * 2 + 1);
            f32x4 c0A = {0.f,0.f,0.f,0.f}, c1A = {0.f,0.f,0.f,0.f};
            f32x4 c0B = {0.f,0.f,0.f,0.f}, c1B = {0.f,0.f,0.f,0.f};
            computeMsg(fa0, c0A, c1A);
            computeMsg(fb0, c0B, c1B);
#pragma unroll
            for (int r = 0; r < 4; ++r) {
                c0A[r] = fmaxf(c0A[r], 0.f); c1A[r] = fmaxf(c1A[r], 0.f);
                c0B[r] = fmaxf(c0B[r], 0.f); c1B[r] = fmaxf(c1B[r], 0.f);
            }
            // msg -> B-fragment (bf16 hi/lo), pure register traffic
            u32x4 Bh0, Bl0, Bh1, Bl1;
            uint2 sp;
            sp = split_pair(c0A[0], c0A[1]); Bh0[0] = sp.x; Bl0[0] = sp.y;
            sp = split_pair(c0A[2], c0A[3]); Bh0[1] = sp.x; Bl0[1] = sp.y;
            sp = split_pair(c0B[0], c0B[1]); Bh0[2] = sp.x; Bl0[2] = sp.y;
            sp = split_pair(c0B[2], c0B[3]); Bh0[3] = sp.x; Bl0[3] = sp.y;
            sp = split_pair(c1A[0], c1A[1]); Bh1[0] = sp.x; Bl1[0] = sp.y;
            sp = split_pair(c1A[2], c1A[3]); Bh1[1] = sp.x; Bl1[1] = sp.y;
            sp = split_pair(c1B[0], c1B[1]); Bh1[2] = sp.x; Bl1[2] = sp.y;
            sp = split_pair(c1B[2], c1B[3]); Bh1[3] = sp.x; Bl1[3] = sp.y;
            // sel A-fragment: row = node l15 (rows 8..15 empty), k = edge
            int tb = e0w + i * 32;
            u32x4 S;
#pragma unroll
            for (int j = 0; j < 4; ++j) {
                int k0 = kb4 + (j & 1) * 2 + ((j >= 2) ? 16 : 0);
                int p0 = tb + k0, p1 = p0 + 1;
                uint32_t s0 = ((unsigned)(p0 - arb) < (unsigned)(are - arb)) ? 0x3F80u : 0u;
                uint32_t s1 = ((unsigned)(p1 - arb) < (unsigned)(are - arb)) ? 0x3F800000u : 0u;
                S[j] = s0 | s1;
            }
            bf16x8 selA = asbf(S);
            aggD0 = MFMA(selA, asbf(Bh0), aggD0);
            aggD0 = MFMA(selA, asbf(Bl0), aggD0);
            aggD1 = MFMA(selA, asbf(Bh1), aggD1);
            aggD1 = MFMA(selA, asbf(Bl1), aggD1);
            fa0 = fa1; fb0 = fb1; fa1 = fan; fb1 = fbn;
        }
    }
    // write agg to LDS: lanes kg<2 hold nodes kg*4+r (rows 0..7)
    if (kg < 2) {
#pragma unroll
        for (int r = 0; r < 4; ++r) {
            int nl = w * 8 + kg * 4 + r;
            sagg[nl * 36 + l15] = aggD0[r];
            sagg[nl * 36 + 16 + l15] = aggD1[r];
        }
    }

    // ---- node phase (wave-local, single pass): lane -> node sg, channels sl*4..+3 ----
    int sg = lane >> 3, sl = lane & 7;
    int nl = w * 8 + sg;
    int n = nb0 + nl;
    if (n < NN) {
        float4 a = make_float4(0.f, 0.f, 0.f, 0.f);
#pragma unroll 8
        for (int k = 0; k < 32; ++k) {
            float xk = shl[nl * 36 + k];
            float4 wv = *(const float4*)(Wn + (size_t)k * 32 + sl * 4);
            a.x = fmaf(xk, wv.x, a.x); a.y = fmaf(xk, wv.y, a.y);
            a.z = fmaf(xk, wv.z, a.z); a.w = fmaf(xk, wv.w, a.w);
        }
#pragma unroll 8
        for (int k = 0; k < 32; ++k) {
            float xk = sagg[nl * 36 + k];
            float4 wv = *(const float4*)(Wn + (size_t)(32 + k) * 32 + sl * 4);
            a.x = fmaf(xk, wv.x, a.x); a.y = fmaf(xk, wv.y, a.y);
            a.z = fmaf(xk, wv.z, a.z); a.w = fmaf(xk, wv.w, a.w);
        }
        {
            float rain = rain0[(size_t)n * T_STEPS + t];
            float4 wv = *(const float4*)(Wn + (size_t)64 * 32 + sl * 4);
            a.x = fmaf(rain, wv.x, a.x); a.y = fmaf(rain, wv.y, a.y);
            a.z = fmaf(rain, wv.z, a.z); a.w = fmaf(rain, wv.w, a.w);
        }
        a.x = fmaxf(a.x, 0.f); a.y = fmaxf(a.y, 0.f);
        a.z = fmaxf(a.z, 0.f); a.w = fmaxf(a.w, 0.f);
        *(float4*)(hnew + (size_t)n * 32 + sl * 4) = a;
        store_hpk(hnpk, n, sl, a);
        if (last) {
            float4 wr = *(const float4*)(Wrain + sl * 4);
            float rv = a.x * wr.x + a.y * wr.y + a.z * wr.z + a.w * wr.w;
            rv += __shfl_xor(rv, 1);
            rv += __shfl_xor(rv, 2);
            rv += __shfl_xor(rv, 4);
            if (sl == 0) out[(size_t)n * T_STEPS + t] = rv;
        }
    }
}

extern "C" void kernel_launch(void* const* d_in, const int* in_sizes, int n_in,
                              void* d_out, int out_size, void* d_ws, size_t ws_size,
                              hipStream_t stream) {
    const float* inputs     = (const float*)d_in[0];
    const float* e_feats    = (const float*)d_in[1];
    const float* rain0      = (const float*)d_in[2];
    const float* W_emb      = (const float*)d_in[3];
    const float* W_edge_in  = (const float*)d_in[4];
    const float* W_node_in  = (const float*)d_in[5];
    const float* W_edge_out = (const float*)d_in[6];
    const float* W_node_out = (const float*)d_in[7];
    const float* W_rain     = (const float*)d_in[8];
    const int*   src        = (const int*)d_in[9];
    const int*   dst        = (const int*)d_in[10];
    float* out = (float*)d_out;

    // workspace layout (~84 MB)
    float* h_a = (float*)d_ws;                                   // NN*32
    float* h_b = h_a + (size_t)NN * 32;                          // NN*32
    uint32_t* hpk_a = (uint32_t*)(h_b + (size_t)NN * 32);        // NN*32 u32
    uint32_t* hpk_b = hpk_a + (size_t)NN * 32;                   // NN*32 u32
    u32x4* ef4      = (u32x4*)(hpk_b + (size_t)NN * 32);         // T*NE u32x4
    u32x4* wfrag    = ef4 + (size_t)T_STEPS * NE;                // 1536
    int* row_ptr    = (int*)(wfrag + 1536);                      // NN+1
    int* deg        = row_ptr + (NN + 1);                        // NN
    int* cnt        = deg + NN;                                  // NN
    uint2* se       = (uint2*)(cnt + NN + 1);                    // NE (8B aligned)
    int* bsum       = (int*)(se + NE);                           // SBLK
    int* btop       = bsum + SBLK;                               // SBLK

    embed_kernel<<<(NN * 8 + 255) / 256, 256, 0, stream>>>(inputs, W_emb, h_a, hpk_a);

    // CSR build (hierarchical scan)
    hipMemsetAsync(deg, 0, (size_t)2 * NN * sizeof(int), stream);  // deg + cnt contiguous
    hist_kernel<<<(NE + 255) / 256, 256, 0, stream>>>(dst, deg);
    scan_part<<<SBLK, 256, 0, stream>>>(deg, bsum);
    scan_tops<<<1, 256, 0, stream>>>(bsum, btop);
    scan_final<<<SBLK, 256, 0, stream>>>(deg, btop, row_ptr);
    scatter_kernel<<<(NE + 255) / 256, 256, 0, stream>>>(src, dst, row_ptr, cnt, se);
    ef_sort_kernel<<<(NE + 255) / 256, 256, 0, stream>>>(e_feats, se, ef4);
    wefrag_kernel<<<6, 256, 0, stream>>>(W_edge_in, W_edge_out, wfrag);

    float* hc = h_a;  float* hn = h_b;
    uint32_t* pkc = hpk_a; uint32_t* pkn = hpk_b;
    for (int t = 0; t < T_STEPS; ++t) {
        const u32x4* ef4_t = ef4 + (size_t)t * NE;
        for (int s = 0; s < 3; ++s) {
            int mat = (s < 2) ? s : 2;
            const float* Wn = (s < 2) ? (W_node_in + (size_t)s * 65 * 32) : W_node_out;
            layer_kernel<<<NBLK, 256, 0, stream>>>(hc, pkc, ef4_t, se, row_ptr, rain0,
                                                   wfrag + (size_t)mat * 512, Wn, W_rain,
                                                   hn, pkn, out, t, (s == 2) ? 1 : 0);
            float* tf = hc; hc = hn; hn = tf;
            uint32_t* tp = pkc; pkc = pkn; pkn = tp;
        }
    }
}